// Round 3
// baseline (37.572 us; speedup 1.0000x reference)
//
#include <hip/hip_runtime.h>
#include <cmath>

// Problem constants (match reference)
constexpr int kC  = 3;
constexpr int kH  = 224;
constexpr int kW  = 224;
constexpr int kNB = 8;     // NUM_BASIS
constexpr int kBS = 56;    // BASIS_SIZE
constexpr int kNF = 256;   // S*T frames
constexpr float kEps = 0.1f;

constexpr int kCHW       = kC * kH * kW;   // 150528
constexpr int kPosG      = kCHW / 4;       // 37632 float4-groups per frame
constexpr int kPosBlocks = kPosG / 256;    // 147
constexpr int kFChunk    = 32;             // frames per thread
constexpr int kNChunk    = kNF / kFChunk;  // 8

// Native clang vector type — required by __builtin_nontemporal_store
// (HIP's float4 is a class and is rejected by the builtin).
typedef float f32x4 __attribute__((ext_vector_type(4)));

// Fused: bilinear-upsample (half-pixel, clamp edges) + tanh-coeff weighted sum
// over 8 bases + clip. One thread handles 4 consecutive w positions (one
// float4 of output) for a 32-frame chunk. Output stores are non-temporal:
// the 154 MB output stream is write-once/never-read, so bypass L2.
__global__ __launch_bounds__(256) void vfa_fused(
    const float* __restrict__ basis,  // (8, 3, 56, 56)
    const float* __restrict__ tc,     // (8, 256)
    float* __restrict__ out)          // (256, 3, 224, 224)
{
  __shared__ float scoef[kFChunk * kNB];  // [frame_local][basis]

  const int tid      = threadIdx.x;
  const int chunk    = blockIdx.x % kNChunk;
  const int posBlock = blockIdx.x / kNChunk;
  const int f0       = chunk * kFChunk;

  // 256 threads fill 256 tanh'd coeffs: scoef[fl*8+b]
  {
    const int fl = tid >> 3, b = tid & 7;
    scoef[tid] = tanhf(tc[b * kNF + f0 + fl]);
  }
  __syncthreads();

  const int pos = posBlock * 256 + tid;  // 0..37631
  const int w4  = pos % 56;              // which float4 group in the row
  const int t1  = pos / 56;              // c*224 + h
  const int h   = t1 % kH;
  const int c   = t1 / kH;

  // Vertical bilinear: in_y = (h+0.5)/4 - 0.5 = h/4 + (h%4)/4 - 0.375
  const int   hh = h >> 2, hm = h & 3;
  const int   y0 = (hm < 2) ? hh - 1 : hh;
  const float fy = (hm == 0) ? 0.625f : (hm == 1) ? 0.875f
                 : (hm == 2) ? 0.125f : 0.375f;
  const int ya = (y0 < 0) ? 0 : y0;
  const int yb = (y0 + 1 > kBS - 1) ? (kBS - 1) : (y0 + 1);

  // Horizontal: w = 4*k + j, j=0..3 -> fx = {0.625,0.875,0.125,0.375},
  // cols (k-1,k) for j<2, (k,k+1) for j>=2, clamped.
  const int k   = w4;
  const int km1 = (k > 0) ? k - 1 : 0;
  const int kp1 = (k < kBS - 1) ? k + 1 : k;

  float v[kNB][4];  // interpolated basis values: [basis][j]
#pragma unroll
  for (int b = 0; b < kNB; ++b) {
    const float* bp = basis + (size_t)((b * kC + c) * kBS) * kBS;
    const float a0 = bp[ya * kBS + km1];
    const float a1 = bp[ya * kBS + k];
    const float a2 = bp[ya * kBS + kp1];
    const float b0 = bp[yb * kBS + km1];
    const float b1 = bp[yb * kBS + k];
    const float b2 = bp[yb * kBS + kp1];

    const float ta0 = 0.375f * a0 + 0.625f * a1;
    const float ta1 = 0.125f * a0 + 0.875f * a1;
    const float ta2 = 0.875f * a1 + 0.125f * a2;
    const float ta3 = 0.625f * a1 + 0.375f * a2;
    const float tb0 = 0.375f * b0 + 0.625f * b1;
    const float tb1 = 0.125f * b0 + 0.875f * b1;
    const float tb2 = 0.875f * b1 + 0.125f * b2;
    const float tb3 = 0.625f * b1 + 0.375f * b2;

    v[b][0] = ta0 + fy * (tb0 - ta0);
    v[b][1] = ta1 + fy * (tb1 - ta1);
    v[b][2] = ta2 + fy * (tb2 - ta2);
    v[b][3] = ta3 + fy * (tb3 - ta3);
  }

  float* optr = out + (size_t)f0 * kCHW + (size_t)pos * 4;
#pragma unroll 4
  for (int fl = 0; fl < kFChunk; ++fl) {
    const float4 cA = *reinterpret_cast<const float4*>(&scoef[fl * 8]);
    const float4 cB = *reinterpret_cast<const float4*>(&scoef[fl * 8 + 4]);
    f32x4 acc;
#pragma unroll
    for (int j = 0; j < 4; ++j) {
      float a = v[0][j] * cA.x;
      a = fmaf(v[1][j], cA.y, a);
      a = fmaf(v[2][j], cA.z, a);
      a = fmaf(v[3][j], cA.w, a);
      a = fmaf(v[4][j], cB.x, a);
      a = fmaf(v[5][j], cB.y, a);
      a = fmaf(v[6][j], cB.z, a);
      a = fmaf(v[7][j], cB.w, a);
      acc[j] = fminf(fmaxf(a, -kEps), kEps);
    }
    __builtin_nontemporal_store(acc, reinterpret_cast<f32x4*>(optr));
    optr += kCHW;
  }
}

extern "C" void kernel_launch(void* const* d_in, const int* in_sizes, int n_in,
                              void* d_out, int out_size, void* d_ws, size_t ws_size,
                              hipStream_t stream) {
  const float* basis = (const float*)d_in[0];  // (8,3,56,56) fp32
  const float* tc    = (const float*)d_in[1];  // (8,256) fp32
  float* out         = (float*)d_out;          // (256,3,224,224) fp32

  dim3 grid(kNChunk * kPosBlocks);  // 8 * 147 = 1176 blocks
  dim3 block(256);
  vfa_fused<<<grid, block, 0, stream>>>(basis, tc, out);
}

// Round 4
// 33.936 us; speedup vs baseline: 1.1072x; 1.1072x over previous
//
#include <hip/hip_runtime.h>
#include <cmath>

// Problem constants (match reference)
constexpr int kC  = 3;
constexpr int kH  = 224;
constexpr int kW  = 224;
constexpr int kNB = 8;     // NUM_BASIS
constexpr int kBS = 56;    // BASIS_SIZE
constexpr int kNF = 256;   // S*T frames
constexpr float kEps = 0.1f;

constexpr int kCHW       = kC * kH * kW;   // 150528
constexpr int kPosG      = kCHW / 4;       // 37632 float4-groups per frame
constexpr int kPosBlocks = kPosG / 256;    // 147
constexpr int kFChunk    = 16;             // frames per thread (16 -> 2352 blocks, ~9.2/CU)
constexpr int kNChunk    = kNF / kFChunk;  // 16

// Fused: bilinear-upsample (half-pixel, clamp edges) + tanh-coeff weighted sum
// over 8 bases + clip. One thread handles 4 consecutive w positions (one
// float4 of output) for a kFChunk-frame chunk.
// NOTE: plain (cached) stores — __builtin_nontemporal_store REGRESSED
// 32.35 -> 37.57 us on gfx950; L2 write-back streams better than nt.
__global__ __launch_bounds__(256) void vfa_fused(
    const float* __restrict__ basis,  // (8, 3, 56, 56)
    const float* __restrict__ tc,     // (8, 256)
    float* __restrict__ out)          // (256, 3, 224, 224)
{
  __shared__ float scoef[kFChunk * kNB];  // [frame_local][basis]

  const int tid      = threadIdx.x;
  const int chunk    = blockIdx.x % kNChunk;
  const int posBlock = blockIdx.x / kNChunk;
  const int f0       = chunk * kFChunk;

  // First kFChunk*8 threads fill the tanh'd coeffs: scoef[fl*8+b]
  if (tid < kFChunk * kNB) {
    const int fl = tid >> 3, b = tid & 7;
    scoef[tid] = tanhf(tc[b * kNF + f0 + fl]);
  }
  __syncthreads();

  const int pos = posBlock * 256 + tid;  // 0..37631
  const int w4  = pos % 56;              // which float4 group in the row
  const int t1  = pos / 56;              // c*224 + h
  const int h   = t1 % kH;
  const int c   = t1 / kH;

  // Vertical bilinear: in_y = (h+0.5)/4 - 0.5 = h/4 + (h%4)/4 - 0.375
  const int   hh = h >> 2, hm = h & 3;
  const int   y0 = (hm < 2) ? hh - 1 : hh;
  const float fy = (hm == 0) ? 0.625f : (hm == 1) ? 0.875f
                 : (hm == 2) ? 0.125f : 0.375f;
  const int ya = (y0 < 0) ? 0 : y0;
  const int yb = (y0 + 1 > kBS - 1) ? (kBS - 1) : (y0 + 1);

  // Horizontal: w = 4*k + j, j=0..3 -> fx = {0.625,0.875,0.125,0.375},
  // cols (k-1,k) for j<2, (k,k+1) for j>=2, clamped.
  const int k   = w4;
  const int km1 = (k > 0) ? k - 1 : 0;
  const int kp1 = (k < kBS - 1) ? k + 1 : k;

  float v[kNB][4];  // interpolated basis values: [basis][j]
#pragma unroll
  for (int b = 0; b < kNB; ++b) {
    const float* bp = basis + (size_t)((b * kC + c) * kBS) * kBS;
    const float a0 = bp[ya * kBS + km1];
    const float a1 = bp[ya * kBS + k];
    const float a2 = bp[ya * kBS + kp1];
    const float b0 = bp[yb * kBS + km1];
    const float b1 = bp[yb * kBS + k];
    const float b2 = bp[yb * kBS + kp1];

    const float ta0 = 0.375f * a0 + 0.625f * a1;
    const float ta1 = 0.125f * a0 + 0.875f * a1;
    const float ta2 = 0.875f * a1 + 0.125f * a2;
    const float ta3 = 0.625f * a1 + 0.375f * a2;
    const float tb0 = 0.375f * b0 + 0.625f * b1;
    const float tb1 = 0.125f * b0 + 0.875f * b1;
    const float tb2 = 0.875f * b1 + 0.125f * b2;
    const float tb3 = 0.625f * b1 + 0.375f * b2;

    v[b][0] = ta0 + fy * (tb0 - ta0);
    v[b][1] = ta1 + fy * (tb1 - ta1);
    v[b][2] = ta2 + fy * (tb2 - ta2);
    v[b][3] = ta3 + fy * (tb3 - ta3);
  }

  float* optr = out + (size_t)f0 * kCHW + (size_t)pos * 4;
#pragma unroll 4
  for (int fl = 0; fl < kFChunk; ++fl) {
    const float4 cA = *reinterpret_cast<const float4*>(&scoef[fl * 8]);
    const float4 cB = *reinterpret_cast<const float4*>(&scoef[fl * 8 + 4]);
    float acc[4];
#pragma unroll
    for (int j = 0; j < 4; ++j) {
      float a = v[0][j] * cA.x;
      a = fmaf(v[1][j], cA.y, a);
      a = fmaf(v[2][j], cA.z, a);
      a = fmaf(v[3][j], cA.w, a);
      a = fmaf(v[4][j], cB.x, a);
      a = fmaf(v[5][j], cB.y, a);
      a = fmaf(v[6][j], cB.z, a);
      a = fmaf(v[7][j], cB.w, a);
      acc[j] = fminf(fmaxf(a, -kEps), kEps);
    }
    *reinterpret_cast<float4*>(optr) = make_float4(acc[0], acc[1], acc[2], acc[3]);
    optr += kCHW;
  }
}

extern "C" void kernel_launch(void* const* d_in, const int* in_sizes, int n_in,
                              void* d_out, int out_size, void* d_ws, size_t ws_size,
                              hipStream_t stream) {
  const float* basis = (const float*)d_in[0];  // (8,3,56,56) fp32
  const float* tc    = (const float*)d_in[1];  // (8,256) fp32
  float* out         = (float*)d_out;          // (256,3,224,224) fp32

  dim3 grid(kNChunk * kPosBlocks);  // 16 * 147 = 2352 blocks
  dim3 block(256);
  vfa_fused<<<grid, block, 0, stream>>>(basis, tc, out);
}

// Round 5
// 32.233 us; speedup vs baseline: 1.1657x; 1.0528x over previous
//
#include <hip/hip_runtime.h>
#include <cmath>

// Problem constants (match reference)
constexpr int kC  = 3;
constexpr int kH  = 224;
constexpr int kW  = 224;
constexpr int kNB = 8;     // NUM_BASIS
constexpr int kBS = 56;    // BASIS_SIZE
constexpr int kNF = 256;   // S*T frames
constexpr float kEps = 0.1f;

constexpr int kCHW       = kC * kH * kW;   // 150528
constexpr int kPosG      = kCHW / 4;       // 37632 float4-groups per frame
constexpr int kPosBlocks = kPosG / 256;    // 147
constexpr int kFChunk    = 32;             // frames per thread — best measured (32f=32.35us, 16f=33.94us)
constexpr int kNChunk    = kNF / kFChunk;  // 8

// Fused: bilinear-upsample (half-pixel, clamp edges) + tanh-coeff weighted sum
// over 8 bases + clip. One thread handles 4 consecutive w positions (one
// float4 of output) for a 32-frame chunk.
// Measured ledger:
//   kFChunk=32, plain stores : 32.35 us  <- this version (best)
//   kFChunk=32, nt stores    : 37.57 us  (nt bypasses L2 write-combining — anti-win)
//   kFChunk=16, plain stores : 33.94 us  (2x blocks -> 2x aggregate prologue)
// Body is at the write-BW ceiling: 154.1 MB / 6.85 TB/s (fill-kernel dispatch
// BW on this chip) = 22.5 us; remaining ~10 us is fixed replay overhead.
__global__ __launch_bounds__(256) void vfa_fused(
    const float* __restrict__ basis,  // (8, 3, 56, 56)
    const float* __restrict__ tc,     // (8, 256)
    float* __restrict__ out)          // (256, 3, 224, 224)
{
  __shared__ float scoef[kFChunk * kNB];  // [frame_local][basis]

  const int tid      = threadIdx.x;
  const int chunk    = blockIdx.x % kNChunk;
  const int posBlock = blockIdx.x / kNChunk;
  const int f0       = chunk * kFChunk;

  // 256 threads fill 256 tanh'd coeffs: scoef[fl*8+b]
  {
    const int fl = tid >> 3, b = tid & 7;
    scoef[tid] = tanhf(tc[b * kNF + f0 + fl]);
  }
  __syncthreads();

  const int pos = posBlock * 256 + tid;  // 0..37631
  const int w4  = pos % 56;              // which float4 group in the row
  const int t1  = pos / 56;              // c*224 + h
  const int h   = t1 % kH;
  const int c   = t1 / kH;

  // Vertical bilinear: in_y = (h+0.5)/4 - 0.5 = h/4 + (h%4)/4 - 0.375
  const int   hh = h >> 2, hm = h & 3;
  const int   y0 = (hm < 2) ? hh - 1 : hh;
  const float fy = (hm == 0) ? 0.625f : (hm == 1) ? 0.875f
                 : (hm == 2) ? 0.125f : 0.375f;
  const int ya = (y0 < 0) ? 0 : y0;
  const int yb = (y0 + 1 > kBS - 1) ? (kBS - 1) : (y0 + 1);

  // Horizontal: w = 4*k + j, j=0..3 -> fx = {0.625,0.875,0.125,0.375},
  // cols (k-1,k) for j<2, (k,k+1) for j>=2, clamped.
  const int k   = w4;
  const int km1 = (k > 0) ? k - 1 : 0;
  const int kp1 = (k < kBS - 1) ? k + 1 : k;

  float v[kNB][4];  // interpolated basis values: [basis][j]
#pragma unroll
  for (int b = 0; b < kNB; ++b) {
    const float* bp = basis + (size_t)((b * kC + c) * kBS) * kBS;
    const float a0 = bp[ya * kBS + km1];
    const float a1 = bp[ya * kBS + k];
    const float a2 = bp[ya * kBS + kp1];
    const float b0 = bp[yb * kBS + km1];
    const float b1 = bp[yb * kBS + k];
    const float b2 = bp[yb * kBS + kp1];

    const float ta0 = 0.375f * a0 + 0.625f * a1;
    const float ta1 = 0.125f * a0 + 0.875f * a1;
    const float ta2 = 0.875f * a1 + 0.125f * a2;
    const float ta3 = 0.625f * a1 + 0.375f * a2;
    const float tb0 = 0.375f * b0 + 0.625f * b1;
    const float tb1 = 0.125f * b0 + 0.875f * b1;
    const float tb2 = 0.875f * b1 + 0.125f * b2;
    const float tb3 = 0.625f * b1 + 0.375f * b2;

    v[b][0] = ta0 + fy * (tb0 - ta0);
    v[b][1] = ta1 + fy * (tb1 - ta1);
    v[b][2] = ta2 + fy * (tb2 - ta2);
    v[b][3] = ta3 + fy * (tb3 - ta3);
  }

  float* optr = out + (size_t)f0 * kCHW + (size_t)pos * 4;
#pragma unroll 4
  for (int fl = 0; fl < kFChunk; ++fl) {
    const float4 cA = *reinterpret_cast<const float4*>(&scoef[fl * 8]);
    const float4 cB = *reinterpret_cast<const float4*>(&scoef[fl * 8 + 4]);
    float acc[4];
#pragma unroll
    for (int j = 0; j < 4; ++j) {
      float a = v[0][j] * cA.x;
      a = fmaf(v[1][j], cA.y, a);
      a = fmaf(v[2][j], cA.z, a);
      a = fmaf(v[3][j], cA.w, a);
      a = fmaf(v[4][j], cB.x, a);
      a = fmaf(v[5][j], cB.y, a);
      a = fmaf(v[6][j], cB.z, a);
      a = fmaf(v[7][j], cB.w, a);
      acc[j] = fminf(fmaxf(a, -kEps), kEps);
    }
    *reinterpret_cast<float4*>(optr) = make_float4(acc[0], acc[1], acc[2], acc[3]);
    optr += kCHW;
  }
}

extern "C" void kernel_launch(void* const* d_in, const int* in_sizes, int n_in,
                              void* d_out, int out_size, void* d_ws, size_t ws_size,
                              hipStream_t stream) {
  const float* basis = (const float*)d_in[0];  // (8,3,56,56) fp32
  const float* tc    = (const float*)d_in[1];  // (8,256) fp32
  float* out         = (float*)d_out;          // (256,3,224,224) fp32

  dim3 grid(kNChunk * kPosBlocks);  // 8 * 147 = 1176 blocks
  dim3 block(256);
  vfa_fused<<<grid, block, 0, stream>>>(basis, tc, out);
}